// Round 1
// baseline (2571.657 us; speedup 1.0000x reference)
//
#include <hip/hip_runtime.h>
#include <cstddef>

#define THREADS 256

// ---------------------------------------------------------------------------
// NT-GEMM: C[i][j] = sum_k A[i][k] * B[j][k]  (+ bias[j] if BIAS)
// A: (M,K) row-major, B: (N,K) row-major, C: (M,N) row-major.
// Tile 128x128, BK=16, 256 threads, 8x8 accumulators per thread.
// LDS stored k-major [kk][row] with +4 pad (stride 132 floats = 528 B, 16B
// aligned) so fragment reads are aligned float4 with <=4-way bank aliasing.
// M,N,K all multiples of tile sizes for this problem (32768/1024/1024).
// ---------------------------------------------------------------------------
template<bool BIAS>
__global__ __launch_bounds__(THREADS, 2)
void gemm_nt_kernel(const float* __restrict__ A, const float* __restrict__ B,
                    const float* __restrict__ bias, float* __restrict__ C,
                    int M, int N, int K)
{
    __shared__ float As[16][132];
    __shared__ float Bs[16][132];
    const int t    = threadIdx.x;
    const int row0 = blockIdx.y * 128;
    const int col0 = blockIdx.x * 128;
    const int tx = t & 15;        // col group: cols 8*tx..8*tx+7
    const int ty = t >> 4;        // row group: rows 8*ty..8*ty+7
    const int lr = t >> 2;        // staging row 0..63 (and +64)
    const int lk = (t & 3) << 2;  // staging k {0,4,8,12}

    float acc[8][8];
#pragma unroll
    for (int i = 0; i < 8; ++i)
#pragma unroll
        for (int j = 0; j < 8; ++j) acc[i][j] = 0.f;

    const float* Ap0 = A + (size_t)(row0 + lr) * K + lk;
    const float* Ap1 = Ap0 + (size_t)64 * K;
    const float* Bp0 = B + (size_t)(col0 + lr) * K + lk;
    const float* Bp1 = Bp0 + (size_t)64 * K;

    for (int k0 = 0; k0 < K; k0 += 16) {
        float4 a0 = *(const float4*)(Ap0 + k0);
        float4 a1 = *(const float4*)(Ap1 + k0);
        float4 b0 = *(const float4*)(Bp0 + k0);
        float4 b1 = *(const float4*)(Bp1 + k0);
        __syncthreads();
        As[lk+0][lr]    = a0.x; As[lk+1][lr]    = a0.y; As[lk+2][lr]    = a0.z; As[lk+3][lr]    = a0.w;
        As[lk+0][lr+64] = a1.x; As[lk+1][lr+64] = a1.y; As[lk+2][lr+64] = a1.z; As[lk+3][lr+64] = a1.w;
        Bs[lk+0][lr]    = b0.x; Bs[lk+1][lr]    = b0.y; Bs[lk+2][lr]    = b0.z; Bs[lk+3][lr]    = b0.w;
        Bs[lk+0][lr+64] = b1.x; Bs[lk+1][lr+64] = b1.y; Bs[lk+2][lr+64] = b1.z; Bs[lk+3][lr+64] = b1.w;
        __syncthreads();
#pragma unroll
        for (int kk = 0; kk < 16; ++kk) {
            float4 av0 = *(const float4*)&As[kk][8*ty];
            float4 av1 = *(const float4*)&As[kk][8*ty+4];
            float4 bv0 = *(const float4*)&Bs[kk][8*tx];
            float4 bv1 = *(const float4*)&Bs[kk][8*tx+4];
            float a[8] = {av0.x,av0.y,av0.z,av0.w,av1.x,av1.y,av1.z,av1.w};
            float b[8] = {bv0.x,bv0.y,bv0.z,bv0.w,bv1.x,bv1.y,bv1.z,bv1.w};
#pragma unroll
            for (int i = 0; i < 8; ++i)
#pragma unroll
                for (int j = 0; j < 8; ++j)
                    acc[i][j] = fmaf(a[i], b[j], acc[i][j]);
        }
    }

    float badd[8];
#pragma unroll
    for (int j = 0; j < 8; ++j) badd[j] = 0.f;
    if (BIAS) {
        float4 c0 = *(const float4*)&bias[col0 + 8*tx];
        float4 c1 = *(const float4*)&bias[col0 + 8*tx + 4];
        badd[0]=c0.x; badd[1]=c0.y; badd[2]=c0.z; badd[3]=c0.w;
        badd[4]=c1.x; badd[5]=c1.y; badd[6]=c1.z; badd[7]=c1.w;
    }
#pragma unroll
    for (int i = 0; i < 8; ++i) {
        float* Cp = C + (size_t)(row0 + 8*ty + i) * N + col0 + 8*tx;
        float4 o0 = make_float4(acc[i][0]+badd[0], acc[i][1]+badd[1],
                                acc[i][2]+badd[2], acc[i][3]+badd[3]);
        float4 o1 = make_float4(acc[i][4]+badd[4], acc[i][5]+badd[5],
                                acc[i][6]+badd[6], acc[i][7]+badd[7]);
        *(float4*)(Cp)     = o0;
        *(float4*)(Cp + 4) = o1;
    }
}

// ---------------------------------------------------------------------------
// Fused middle: per block of 32 rows (grid 1024):
//  A) glogit[32][256] = q_tile @ routers^T  (col 255 zero-padded, never used)
//  B) gates = sigmoid(glogit) -> LDS Gs
//  C) leaf_prob[32][256] via 8-level tree product -> LDS Ps
//  D) ret[32][1024] = Ps @ leaf_values, written IN-PLACE over the q rows
// LDS regions aliased: total 66048 B -> 2 blocks/CU.
//   [0 .. 8320)    floats : Gs[32][256] (phases B/C), then Vs[32][260] (D)
//   [8320 .. 16512) floats: Qs[16][36]+Rs[16][260] (A), then Ps[32][256] (C/D)
// ---------------------------------------------------------------------------
__global__ __launch_bounds__(THREADS, 2)
void middle_kernel(float* __restrict__ q,
                   const float* __restrict__ routers,
                   const float* __restrict__ leafV)
{
    __shared__ __align__(16) float smem[16512];
    float (*Gs)[256] = (float (*)[256])(smem);
    float (*Vs)[260] = (float (*)[260])(smem);
    float (*Ps)[256] = (float (*)[256])(smem + 8320);
    float (*Qs)[36]  = (float (*)[36]) (smem + 8320);
    float (*Rs)[260] = (float (*)[260])(smem + 8896);

    const int t    = threadIdx.x;
    const int row0 = blockIdx.x * 32;
    const int tx = t & 31;   // col group: cols 8*tx..8*tx+7
    const int ty = t >> 5;   // row group: rows 4*ty..4*ty+3

    // ---------------- Phase A: gate logits ----------------
    float acc[4][8];
#pragma unroll
    for (int i = 0; i < 4; ++i)
#pragma unroll
        for (int j = 0; j < 8; ++j) acc[i][j] = 0.f;

    const int ar = t >> 3;        // q staging row 0..31
    const int ak = (t & 7) << 1;  // q staging k {0,2,...,14}
    const float* qrow = q + (size_t)(row0 + ar) * 1024 + ak;
    const float* rrow = routers + (size_t)t * 1024;   // valid only if t < 255

    for (int k0 = 0; k0 < 1024; k0 += 16) {
        float2 qv = *(const float2*)(qrow + k0);
        float4 r0 = make_float4(0,0,0,0), r1 = r0, r2 = r0, r3 = r0;
        if (t < 255) {
            r0 = *(const float4*)(rrow + k0);
            r1 = *(const float4*)(rrow + k0 + 4);
            r2 = *(const float4*)(rrow + k0 + 8);
            r3 = *(const float4*)(rrow + k0 + 12);
        }
        __syncthreads();
        Qs[ak][ar] = qv.x; Qs[ak+1][ar] = qv.y;
        Rs[0][t]=r0.x;  Rs[1][t]=r0.y;  Rs[2][t]=r0.z;  Rs[3][t]=r0.w;
        Rs[4][t]=r1.x;  Rs[5][t]=r1.y;  Rs[6][t]=r1.z;  Rs[7][t]=r1.w;
        Rs[8][t]=r2.x;  Rs[9][t]=r2.y;  Rs[10][t]=r2.z; Rs[11][t]=r2.w;
        Rs[12][t]=r3.x; Rs[13][t]=r3.y; Rs[14][t]=r3.z; Rs[15][t]=r3.w;
        __syncthreads();
#pragma unroll
        for (int kk = 0; kk < 16; ++kk) {
            float4 qa  = *(const float4*)&Qs[kk][4*ty];
            float4 rb0 = *(const float4*)&Rs[kk][8*tx];
            float4 rb1 = *(const float4*)&Rs[kk][8*tx+4];
            float a[4] = {qa.x,qa.y,qa.z,qa.w};
            float b[8] = {rb0.x,rb0.y,rb0.z,rb0.w,rb1.x,rb1.y,rb1.z,rb1.w};
#pragma unroll
            for (int i = 0; i < 4; ++i)
#pragma unroll
                for (int j = 0; j < 8; ++j)
                    acc[i][j] = fmaf(a[i], b[j], acc[i][j]);
        }
    }

    // ---------------- Phase B: sigmoid -> Gs ----------------
    // Gs region [0..8320) does not alias Qs/Rs [8320..), so no barrier needed
    // before the writes; barrier below orders writes vs phase-C reads.
#pragma unroll
    for (int i = 0; i < 4; ++i)
#pragma unroll
        for (int j = 0; j < 8; ++j)
            Gs[4*ty+i][8*tx+j] = 1.f / (1.f + expf(-acc[i][j]));
    __syncthreads();

    // ---------------- Phase C: tree product -> Ps ----------------
    {
        const int m = t;  // leaf index
        for (int r = 0; r < 32; ++r) {
            float lp = 1.f;
#pragma unroll
            for (int l = 0; l < 8; ++l) {
                int gidx = (1 << l) - 1 + (m >> (8 - l));
                float g  = Gs[r][gidx];
                lp *= ((m >> (7 - l)) & 1) ? g : (1.f - g);
            }
            Ps[r][m] = lp;
        }
    }
    __syncthreads();

    // ---------------- Phase D: ret = Ps @ leaf_values (in-place) ----------------
    const int vk = t >> 3;          // V staging leaf-row 0..31
    const int vc = (t & 7) << 5;    // V staging col base {0,32,...,224}
    for (int cc = 0; cc < 4; ++cc) {
        float acc2[4][8];
#pragma unroll
        for (int i = 0; i < 4; ++i)
#pragma unroll
            for (int j = 0; j < 8; ++j) acc2[i][j] = 0.f;

        for (int k0 = 0; k0 < 256; k0 += 32) {
            float4 vv[8];
            const float* vrow = leafV + (size_t)(k0 + vk) * 1024 + cc*256 + vc;
#pragma unroll
            for (int j = 0; j < 8; ++j) vv[j] = *(const float4*)(vrow + 4*j);
            __syncthreads();   // prev Vs readers done (also orders vs phase C, Gs dead after)
#pragma unroll
            for (int j = 0; j < 8; ++j) *(float4*)&Vs[vk][vc + 4*j] = vv[j];
            __syncthreads();
#pragma unroll
            for (int kk = 0; kk < 32; ++kk) {
                float4 vb0 = *(const float4*)&Vs[kk][8*tx];
                float4 vb1 = *(const float4*)&Vs[kk][8*tx+4];
                float b[8] = {vb0.x,vb0.y,vb0.z,vb0.w,vb1.x,vb1.y,vb1.z,vb1.w};
#pragma unroll
                for (int i = 0; i < 4; ++i) {
                    float p = Ps[4*ty+i][k0+kk];
#pragma unroll
                    for (int j = 0; j < 8; ++j)
                        acc2[i][j] = fmaf(p, b[j], acc2[i][j]);
                }
            }
        }
#pragma unroll
        for (int i = 0; i < 4; ++i) {
            float* op = q + (size_t)(row0 + 4*ty + i) * 1024 + cc*256 + 8*tx;
            *(float4*)(op)   = make_float4(acc2[i][0],acc2[i][1],acc2[i][2],acc2[i][3]);
            *(float4*)(op+4) = make_float4(acc2[i][4],acc2[i][5],acc2[i][6],acc2[i][7]);
        }
    }
}

// ---------------------------------------------------------------------------
// inputs: 0=x (8,4096,1024) f32, 1=Wq (1024,1024), 2=routers (255,1024),
//         3=leaf_keys (256,1024) UNUSED by reference, 4=leaf_values (256,1024),
//         5=Wout_w (1024,1024), 6=Wout_b (1024,)
// out: (8,4096,1024) f32.  ws: 128 MiB used for q/ret buffer (in-place reuse).
// ---------------------------------------------------------------------------
extern "C" void kernel_launch(void* const* d_in, const int* in_sizes, int n_in,
                              void* d_out, int out_size, void* d_ws, size_t ws_size,
                              hipStream_t stream) {
    (void)in_sizes; (void)n_in; (void)out_size; (void)ws_size;
    const float* x       = (const float*)d_in[0];
    const float* Wq      = (const float*)d_in[1];
    const float* routers = (const float*)d_in[2];
    const float* leafV   = (const float*)d_in[4];
    const float* WoutW   = (const float*)d_in[5];
    const float* WoutB   = (const float*)d_in[6];
    float* out  = (float*)d_out;
    float* qbuf = (float*)d_ws;           // 32768*1024 f32 = 128 MiB

    const int BT = 32768, D = 1024;
    dim3 blk(THREADS);
    dim3 g_gemm(D / 128, BT / 128);       // (8, 256)

    // q = x @ Wq^T
    gemm_nt_kernel<false><<<g_gemm, blk, 0, stream>>>(x, Wq, nullptr, qbuf, BT, D, D);
    // gates -> leaf probs -> ret (in-place over qbuf)
    middle_kernel<<<dim3(BT / 32), blk, 0, stream>>>(qbuf, routers, leafV);
    // out = ret @ Wout^T + b
    gemm_nt_kernel<true><<<g_gemm, blk, 0, stream>>>(qbuf, WoutW, WoutB, out, BT, D, D);
}

// Round 3
// 1897.080 us; speedup vs baseline: 1.3556x; 1.3556x over previous
//
#include <hip/hip_runtime.h>
#include <cstddef>

#define THREADS 256

// R2 resubmit (R2 bench lost to GPUAcquisitionTimeout — no data).
// Big GEMMs -> split-bf16 3-pass MFMA (Ahi*Bhi + Ahi*Blo + Alo*Bhi).
// Weights pre-split to hi/lo bf16 in ws (+8 MB); A-side (x / ret) split
// in-kernel during LDS staging (truncation split, ~5 VALU/float).
// middle_kernel deliberately UNTOUCHED this round.

typedef __bf16 bf16x8 __attribute__((ext_vector_type(8)));
typedef float  f32x4  __attribute__((ext_vector_type(4)));

__device__ __forceinline__ ushort bf_hi(float f) {
    return (ushort)(__float_as_uint(f) >> 16);          // truncation split
}
__device__ __forceinline__ float hi_part(float f) {
    return __uint_as_float(__float_as_uint(f) & 0xffff0000u);
}
__device__ __forceinline__ ushort bf_lo(float f) {
    return (ushort)(__float_as_uint(f - hi_part(f)) >> 16);
}

// ---------------------------------------------------------------------------
// Elementwise fp32 -> (hi, lo) bf16 split, for the weight matrices.
// ---------------------------------------------------------------------------
__global__ void split_hilo_kernel(const float* __restrict__ in,
                                  ushort* __restrict__ hi, ushort* __restrict__ lo,
                                  int n4)
{
    int i = blockIdx.x * blockDim.x + threadIdx.x;
    const int stride = gridDim.x * blockDim.x;
    for (; i < n4; i += stride) {
        float4 v = ((const float4*)in)[i];
        ushort4 h, l;
        h.x = bf_hi(v.x); h.y = bf_hi(v.y); h.z = bf_hi(v.z); h.w = bf_hi(v.w);
        l.x = bf_lo(v.x); l.y = bf_lo(v.y); l.z = bf_lo(v.z); l.w = bf_lo(v.w);
        ((ushort4*)hi)[i] = h;
        ((ushort4*)lo)[i] = l;
    }
}

// ---------------------------------------------------------------------------
// NT-GEMM via MFMA: C[i][j] = sum_k A[i][k]*B[j][k] (+bias[j] if BIAS)
// A fp32 (M,K) row-major, split in-kernel. B pre-split hi/lo bf16 (N,K).
// Tile 128x128, BK=32, 256 threads = 4 waves (2x2), wave tile 64x64,
// 16 frags of 16x16 per wave, mfma_f32_16x16x32_bf16, 3 passes -> 48 MFMA/step.
// LDS [row][32k] ushort (64 B rows): frag b128 reads + staging writes all land
// on the wave64 LDS throughput floor (bank math checked: 8 lanes/bank-quad,
// distinct addrs, == b128 minimum).
// XCD-aware bijective swizzle (nwg % 8 == 0): keeps each A row-panel resident
// in one XCD's L2 (else A is fetched 8x = 1 GB/GEMM).
// ---------------------------------------------------------------------------
template<bool BIAS>
__global__ __launch_bounds__(THREADS, 2)
void gemm_nt_mfma(const float* __restrict__ A,
                  const ushort* __restrict__ Bh, const ushort* __restrict__ Bl,
                  const float* __restrict__ bias, float* __restrict__ C,
                  int M, int N, int K)
{
    __shared__ ushort Ah[128][32], Al[128][32], Bhs[128][32], Bls[128][32];
    const int t = threadIdx.x;

    // XCD swizzle: XCD k owns a contiguous chunk of swizzled ids
    const int gx  = gridDim.x;
    const int nwg = gx * gridDim.y;
    const int lin = blockIdx.y * gx + blockIdx.x;
    const int swz = (lin & 7) * (nwg >> 3) + (lin >> 3);
    const int bx = swz % gx;
    const int by = swz / gx;
    const int row0 = by * 128;
    const int col0 = bx * 128;

    const int wave = t >> 6, lane = t & 63;
    const int wr = wave >> 1, wc = wave & 1;   // 2x2 wave grid
    const int lr16 = lane & 15, kg = lane >> 4;

    f32x4 acc[4][4] = {};

    const int ar  = t >> 3;        // A staging row 0..31 (+32p)
    const int ac4 = t & 7;         // float4 id within 32-k
    const int bnr = t >> 2;        // B staging row 0..63 (+64p)
    const int bk8 = (t & 3) * 8;   // ushort8 id within 32-k

    for (int k0 = 0; k0 < K; k0 += 32) {
        float4 av[4];
#pragma unroll
        for (int p = 0; p < 4; ++p)
            av[p] = *(const float4*)(A + (size_t)(row0 + 32*p + ar) * K + k0 + ac4*4);
        uint4 bhv[2], blv[2];
#pragma unroll
        for (int p = 0; p < 2; ++p) {
            const size_t off = (size_t)(col0 + 64*p + bnr) * K + k0 + bk8;
            bhv[p] = *(const uint4*)(Bh + off);
            blv[p] = *(const uint4*)(Bl + off);
        }
        __syncthreads();   // previous iteration's fragment reads done
#pragma unroll
        for (int p = 0; p < 4; ++p) {
            ushort4 h, l;
            h.x = bf_hi(av[p].x); h.y = bf_hi(av[p].y); h.z = bf_hi(av[p].z); h.w = bf_hi(av[p].w);
            l.x = bf_lo(av[p].x); l.y = bf_lo(av[p].y); l.z = bf_lo(av[p].z); l.w = bf_lo(av[p].w);
            *(ushort4*)&Ah[32*p + ar][ac4*4] = h;
            *(ushort4*)&Al[32*p + ar][ac4*4] = l;
        }
#pragma unroll
        for (int p = 0; p < 2; ++p) {
            *(uint4*)&Bhs[64*p + bnr][bk8] = bhv[p];
            *(uint4*)&Bls[64*p + bnr][bk8] = blv[p];
        }
        __syncthreads();

        bf16x8 ah[4], alo[4], bh[4], blo[4];
#pragma unroll
        for (int m = 0; m < 4; ++m) {
            ah[m]  = *(const bf16x8*)&Ah[wr*64 + m*16 + lr16][kg*8];
            alo[m] = *(const bf16x8*)&Al[wr*64 + m*16 + lr16][kg*8];
        }
#pragma unroll
        for (int n = 0; n < 4; ++n) {
            bh[n]  = *(const bf16x8*)&Bhs[wc*64 + n*16 + lr16][kg*8];
            blo[n] = *(const bf16x8*)&Bls[wc*64 + n*16 + lr16][kg*8];
        }
#pragma unroll
        for (int m = 0; m < 4; ++m)
#pragma unroll
            for (int n = 0; n < 4; ++n) {
                acc[m][n] = __builtin_amdgcn_mfma_f32_16x16x32_bf16(ah[m],  bh[n],  acc[m][n], 0, 0, 0);
                acc[m][n] = __builtin_amdgcn_mfma_f32_16x16x32_bf16(ah[m],  blo[n], acc[m][n], 0, 0, 0);
                acc[m][n] = __builtin_amdgcn_mfma_f32_16x16x32_bf16(alo[m], bh[n],  acc[m][n], 0, 0, 0);
            }
    }

    // epilogue: C/D layout col=lane&15, row=(lane>>4)*4+reg (m89-verified)
    float bv[4] = {0.f, 0.f, 0.f, 0.f};
    if (BIAS) {
#pragma unroll
        for (int n = 0; n < 4; ++n)
            bv[n] = bias[col0 + wc*64 + n*16 + lr16];
    }
#pragma unroll
    for (int m = 0; m < 4; ++m) {
        const int rbase = row0 + wr*64 + m*16 + kg*4;
#pragma unroll
        for (int n = 0; n < 4; ++n) {
            const int col = col0 + wc*64 + n*16 + lr16;
            float* Cp = C + (size_t)rbase * N + col;
#pragma unroll
            for (int j = 0; j < 4; ++j)
                Cp[(size_t)j * N] = acc[m][n][j] + bv[n];
        }
    }
}

// ---------------------------------------------------------------------------
// Fused middle (UNCHANGED from R1): per block of 32 rows (grid 1024):
//  A) glogit[32][256] = q_tile @ routers^T  (col 255 zero-padded, never used)
//  B) gates = sigmoid(glogit) -> LDS Gs
//  C) leaf_prob[32][256] via 8-level tree product -> LDS Ps
//  D) ret[32][1024] = Ps @ leaf_values, written IN-PLACE over the q rows
// ---------------------------------------------------------------------------
__global__ __launch_bounds__(THREADS, 2)
void middle_kernel(float* __restrict__ q,
                   const float* __restrict__ routers,
                   const float* __restrict__ leafV)
{
    __shared__ __align__(16) float smem[16512];
    float (*Gs)[256] = (float (*)[256])(smem);
    float (*Vs)[260] = (float (*)[260])(smem);
    float (*Ps)[256] = (float (*)[256])(smem + 8320);
    float (*Qs)[36]  = (float (*)[36]) (smem + 8320);
    float (*Rs)[260] = (float (*)[260])(smem + 8896);

    const int t    = threadIdx.x;
    const int row0 = blockIdx.x * 32;
    const int tx = t & 31;
    const int ty = t >> 5;

    float acc[4][8];
#pragma unroll
    for (int i = 0; i < 4; ++i)
#pragma unroll
        for (int j = 0; j < 8; ++j) acc[i][j] = 0.f;

    const int ar = t >> 3;
    const int ak = (t & 7) << 1;
    const float* qrow = q + (size_t)(row0 + ar) * 1024 + ak;
    const float* rrow = routers + (size_t)t * 1024;

    for (int k0 = 0; k0 < 1024; k0 += 16) {
        float2 qv = *(const float2*)(qrow + k0);
        float4 r0 = make_float4(0,0,0,0), r1 = r0, r2 = r0, r3 = r0;
        if (t < 255) {
            r0 = *(const float4*)(rrow + k0);
            r1 = *(const float4*)(rrow + k0 + 4);
            r2 = *(const float4*)(rrow + k0 + 8);
            r3 = *(const float4*)(rrow + k0 + 12);
        }
        __syncthreads();
        Qs[ak][ar] = qv.x; Qs[ak+1][ar] = qv.y;
        Rs[0][t]=r0.x;  Rs[1][t]=r0.y;  Rs[2][t]=r0.z;  Rs[3][t]=r0.w;
        Rs[4][t]=r1.x;  Rs[5][t]=r1.y;  Rs[6][t]=r1.z;  Rs[7][t]=r1.w;
        Rs[8][t]=r2.x;  Rs[9][t]=r2.y;  Rs[10][t]=r2.z; Rs[11][t]=r2.w;
        Rs[12][t]=r3.x; Rs[13][t]=r3.y; Rs[14][t]=r3.z; Rs[15][t]=r3.w;
        __syncthreads();
#pragma unroll
        for (int kk = 0; kk < 16; ++kk) {
            float4 qa  = *(const float4*)&Qs[kk][4*ty];
            float4 rb0 = *(const float4*)&Rs[kk][8*tx];
            float4 rb1 = *(const float4*)&Rs[kk][8*tx+4];
            float a[4] = {qa.x,qa.y,qa.z,qa.w};
            float b[8] = {rb0.x,rb0.y,rb0.z,rb0.w,rb1.x,rb1.y,rb1.z,rb1.w};
#pragma unroll
            for (int i = 0; i < 4; ++i)
#pragma unroll
                for (int j = 0; j < 8; ++j)
                    acc[i][j] = fmaf(a[i], b[j], acc[i][j]);
        }
    }

#pragma unroll
    for (int i = 0; i < 4; ++i)
#pragma unroll
        for (int j = 0; j < 8; ++j)
            Gs[4*ty+i][8*tx+j] = 1.f / (1.f + expf(-acc[i][j]));
    __syncthreads();

    {
        const int m = t;
        for (int r = 0; r < 32; ++r) {
            float lp = 1.f;
#pragma unroll
            for (int l = 0; l < 8; ++l) {
                int gidx = (1 << l) - 1 + (m >> (8 - l));
                float g  = Gs[r][gidx];
                lp *= ((m >> (7 - l)) & 1) ? g : (1.f - g);
            }
            Ps[r][m] = lp;
        }
    }
    __syncthreads();

    const int vk = t >> 3;
    const int vc = (t & 7) << 5;
    for (int cc = 0; cc < 4; ++cc) {
        float acc2[4][8];
#pragma unroll
        for (int i = 0; i < 4; ++i)
#pragma unroll
            for (int j = 0; j < 8; ++j) acc2[i][j] = 0.f;

        for (int k0 = 0; k0 < 256; k0 += 32) {
            float4 vv[8];
            const float* vrow = leafV + (size_t)(k0 + vk) * 1024 + cc*256 + vc;
#pragma unroll
            for (int j = 0; j < 8; ++j) vv[j] = *(const float4*)(vrow + 4*j);
            __syncthreads();
#pragma unroll
            for (int j = 0; j < 8; ++j) *(float4*)&Vs[vk][vc + 4*j] = vv[j];
            __syncthreads();
#pragma unroll
            for (int kk = 0; kk < 32; ++kk) {
                float4 vb0 = *(const float4*)&Vs[kk][8*tx];
                float4 vb1 = *(const float4*)&Vs[kk][8*tx+4];
                float b[8] = {vb0.x,vb0.y,vb0.z,vb0.w,vb1.x,vb1.y,vb1.z,vb1.w};
#pragma unroll
                for (int i = 0; i < 4; ++i) {
                    float p = Ps[4*ty+i][k0+kk];
#pragma unroll
                    for (int j = 0; j < 8; ++j)
                        acc2[i][j] = fmaf(p, b[j], acc2[i][j]);
                }
            }
        }
#pragma unroll
        for (int i = 0; i < 4; ++i) {
            float* op = q + (size_t)(row0 + 4*ty + i) * 1024 + cc*256 + 8*tx;
            *(float4*)(op)   = make_float4(acc2[i][0],acc2[i][1],acc2[i][2],acc2[i][3]);
            *(float4*)(op+4) = make_float4(acc2[i][4],acc2[i][5],acc2[i][6],acc2[i][7]);
        }
    }
}

// ---------------------------------------------------------------------------
// inputs: 0=x (8,4096,1024) f32, 1=Wq (1024,1024), 2=routers (255,1024),
//         3=leaf_keys UNUSED, 4=leaf_values (256,1024), 5=Wout_w, 6=Wout_b
// ws layout (bytes): [0,128M) qbuf f32; [128M..) Wq_hi, Wq_lo, Wout_hi,
//                    Wout_lo (2 MB each) -> 136 MB total.
// ---------------------------------------------------------------------------
extern "C" void kernel_launch(void* const* d_in, const int* in_sizes, int n_in,
                              void* d_out, int out_size, void* d_ws, size_t ws_size,
                              hipStream_t stream) {
    (void)in_sizes; (void)n_in; (void)out_size; (void)ws_size;
    const float* x       = (const float*)d_in[0];
    const float* Wq      = (const float*)d_in[1];
    const float* routers = (const float*)d_in[2];
    const float* leafV   = (const float*)d_in[4];
    const float* WoutW   = (const float*)d_in[5];
    const float* WoutB   = (const float*)d_in[6];
    float* out  = (float*)d_out;

    char* ws = (char*)d_ws;
    float*  qbuf  = (float*)ws;                                  // 128 MiB
    ushort* Wqh   = (ushort*)(ws + 134217728);                   // 2 MiB
    ushort* Wql   = (ushort*)(ws + 134217728 + 2097152);
    ushort* Wouth = (ushort*)(ws + 134217728 + 2*2097152);
    ushort* Woutl = (ushort*)(ws + 134217728 + 3*2097152);

    const int BT = 32768, D = 1024;
    dim3 blk(THREADS);
    dim3 g_gemm(D / 128, BT / 128);       // (8, 256) -> 2048 wgs, %8==0

    split_hilo_kernel<<<512, THREADS, 0, stream>>>(Wq,    Wqh,   Wql,   D*D/4);
    split_hilo_kernel<<<512, THREADS, 0, stream>>>(WoutW, Wouth, Woutl, D*D/4);

    // q = x @ Wq^T   (split-bf16 MFMA)
    gemm_nt_mfma<false><<<g_gemm, blk, 0, stream>>>(x, Wqh, Wql, nullptr, qbuf, BT, D, D);
    // gates -> leaf probs -> ret (in-place over qbuf)
    middle_kernel<<<dim3(BT / 32), blk, 0, stream>>>(qbuf, routers, leafV);
    // out = ret @ Wout^T + b   (split-bf16 MFMA)
    gemm_nt_mfma<true><<<g_gemm, blk, 0, stream>>>(qbuf, Wouth, Woutl, WoutB, out, BT, D, D);
}